// Round 6
// baseline (169.040 us; speedup 1.0000x reference)
//
#include <hip/hip_runtime.h>
#include <hip/hip_bf16.h>

typedef __bf16 bf16x8 __attribute__((ext_vector_type(8)));
typedef __bf16 bf16x2 __attribute__((ext_vector_type(2)));
typedef float f32x4 __attribute__((ext_vector_type(4)));

#define K2f 2.0813689810056077f   // log2(e)^2
#define LN2f 0.6931471805599453f

// Kernel 1: prototypes f32 -> bf16 in MFMA B-fragment order + ysq2 = ||y||^2*log2e^2.
// Element e of class c, dim d (d = kk*32 + lg*8 + e) -> bf16 offset
// ((c>>4)*4 + kk)*64*8 + (lg*16 + (c&15))*8 + e.  Tile ct occupies 4096 B.
__global__ void dce_prep(const float* __restrict__ protos,
                         unsigned short* __restrict__ bpf,
                         float* __restrict__ ysq2) {
    int c = blockIdx.x;
    int lane = threadIdx.x;  // dims 2*lane, 2*lane+1
    float2 f = ((const float2*)(protos))[c * 64 + lane];
    int d0 = lane * 2;
    int kk = d0 >> 5, sub = d0 & 31, lg = sub >> 3, e = sub & 7;
    size_t o = (((size_t)((c >> 4) * 4 + kk) * 64) + lg * 16 + (c & 15)) * 8 + e;
    bf16x2 h;
    h.x = (__bf16)f.x;
    h.y = (__bf16)f.y;
    *(bf16x2*)(bpf + o) = h;
    float xs = f.x * f.x + f.y * f.y;
#pragma unroll
    for (int d = 1; d < 64; d <<= 1) xs += __shfl_xor(xs, d);
    if (lane == 0) ysq2[c] = xs * K2f;
}

// Kernel 2: fused distance-softmax-NLL. NO in-loop barriers, NO LDS staging:
// each wave streams frag-ordered B from L1/L2 with a register software
// pipeline (unroll-2, prefetch depth 2). 2048 blocks x 256 threads; wave owns
// 32 rows (2 M-frags). logits <= 0 -> softmax max pinned at 0:
//   nll = dist_label + ln2 * log2( sum_c 2^(-log2e * dist_c) ).
__global__ __launch_bounds__(256, 4) void dce_main(
    const float* __restrict__ feats,
    const float* __restrict__ protos,
    const unsigned short* __restrict__ bpf,
    const float* __restrict__ ysq2,
    const int* __restrict__ labels,
    float* __restrict__ partials, int C) {
    const int tid = threadIdx.x;
    const int lane = tid & 63;
    const int w = tid >> 6;
    const int row0 = blockIdx.x * 128;
    const int rbase = row0 + w * 32;
    const int lr = lane & 15;
    const int lg = lane >> 4;

    // ---- Phase 1: exact f32 label distance, 2 threads per row ----
    const int r1 = row0 + (tid >> 1);
    const int half = tid & 1;
    const int lab = labels[r1];
    const float4* fx = (const float4*)feats + (size_t)r1 * 32 + half * 16;
    const float4* px = (const float4*)protos + (size_t)lab * 32 + half * 16;
    float xx = 0.f, yy = 0.f, xy = 0.f;
#pragma unroll
    for (int i = 0; i < 16; ++i) {
        float4 f = fx[i], p = px[i];
        xx = fmaf(f.x, f.x, fmaf(f.y, f.y, fmaf(f.z, f.z, fmaf(f.w, f.w, xx))));
        yy = fmaf(p.x, p.x, fmaf(p.y, p.y, fmaf(p.z, p.z, fmaf(p.w, p.w, yy))));
        xy = fmaf(f.x, p.x, fmaf(f.y, p.y, fmaf(f.z, p.z, fmaf(f.w, p.w, xy))));
    }
    xx += __shfl_xor(xx, 1);
    yy += __shfl_xor(yy, 1);
    xy += __shfl_xor(xy, 1);
    const float ld = __builtin_amdgcn_sqrtf(fmaxf(fmaf(-2.f, xy, xx + yy), 0.f));

    // ---- A fragments: 2 M-frags x 4 k-slices ----
    bf16x8 a[2][4];
    const float4* f4 = (const float4*)feats;
#pragma unroll
    for (int m = 0; m < 2; ++m) {
        size_t r = (size_t)(rbase + m * 16 + lr);
#pragma unroll
        for (int kk = 0; kk < 4; ++kk) {
            size_t idx = r * 32 + kk * 8 + lg * 2;
            float4 lo = f4[idx];
            float4 hi = f4[idx + 1];
            bf16x8 v;
            v[0] = (__bf16)lo.x; v[1] = (__bf16)lo.y; v[2] = (__bf16)lo.z; v[3] = (__bf16)lo.w;
            v[4] = (__bf16)hi.x; v[5] = (__bf16)hi.y; v[6] = (__bf16)hi.z; v[7] = (__bf16)hi.w;
            a[m][kk] = v;
        }
    }

    // ||x||^2 (scaled) in C/D layout: element (m,reg) covers row m*16+lg*4+reg,
    // whose exact xx lives at lane 2*(that row-in-wave).
    float xsqs[2][4];
#pragma unroll
    for (int m = 0; m < 2; ++m)
#pragma unroll
        for (int reg = 0; reg < 4; ++reg)
            xsqs[m][reg] = K2f * __shfl(xx, 2 * (m * 16 + lg * 4 + reg));

    float lacc[2][4];
#pragma unroll
    for (int m = 0; m < 2; ++m)
#pragma unroll
        for (int reg = 0; reg < 4; ++reg) lacc[m][reg] = 0.f;

    // ---- Main loop: register software pipeline over 64 B tiles ----
    const bf16x8* bv = (const bf16x8*)bpf;
    bf16x8 b0[4], b1[4];
    float yq0, yq1;
#pragma unroll
    for (int kk = 0; kk < 4; ++kk) b0[kk] = bv[kk * 64 + lane];
    yq0 = ysq2[lr];
#pragma unroll
    for (int kk = 0; kk < 4; ++kk) b1[kk] = bv[(4 + kk) * 64 + lane];
    yq1 = ysq2[16 + lr];

    const int nt = C >> 4;  // 64, even
    for (int t = 0; t < nt; t += 2) {
        bf16x8 n0[4], n1[4];
        float m0 = 0.f, m1 = 0.f;
        if (t + 2 < nt) {
#pragma unroll
            for (int kk = 0; kk < 4; ++kk) n0[kk] = bv[((t + 2) * 4 + kk) * 64 + lane];
            m0 = ysq2[(t + 2) * 16 + lr];
#pragma unroll
            for (int kk = 0; kk < 4; ++kk) n1[kk] = bv[((t + 3) * 4 + kk) * 64 + lane];
            m1 = ysq2[(t + 3) * 16 + lr];
        }
#pragma unroll
        for (int u = 0; u < 2; ++u) {
            const bf16x8* b = (u == 0) ? b0 : b1;
            const float yq = (u == 0) ? yq0 : yq1;
            f32x4 acc0 = {0.f, 0.f, 0.f, 0.f};
            f32x4 acc1 = {0.f, 0.f, 0.f, 0.f};
#pragma unroll
            for (int kk = 0; kk < 4; ++kk) {
                acc0 = __builtin_amdgcn_mfma_f32_16x16x32_bf16(a[0][kk], b[kk], acc0, 0, 0, 0);
                acc1 = __builtin_amdgcn_mfma_f32_16x16x32_bf16(a[1][kk], b[kk], acc1, 0, 0, 0);
            }
#pragma unroll
            for (int reg = 0; reg < 4; ++reg) {
                float d0 = fmaf(-2.f * K2f, acc0[reg], xsqs[0][reg] + yq);
                float d1 = fmaf(-2.f * K2f, acc1[reg], xsqs[1][reg] + yq);
                d0 = fmaxf(d0, 0.f);
                d1 = fmaxf(d1, 0.f);
                lacc[0][reg] += __builtin_amdgcn_exp2f(-__builtin_amdgcn_sqrtf(d0));
                lacc[1][reg] += __builtin_amdgcn_exp2f(-__builtin_amdgcn_sqrtf(d1));
            }
        }
#pragma unroll
        for (int kk = 0; kk < 4; ++kk) { b0[kk] = n0[kk]; b1[kk] = n1[kk]; }
        yq0 = m0;
        yq1 = m1;
    }

    // ---- Reduce over 16 column-lanes per row, add exact label distance ----
    float ssum = 0.f;
#pragma unroll
    for (int m = 0; m < 2; ++m)
#pragma unroll
        for (int reg = 0; reg < 4; ++reg) {
            float l = lacc[m][reg];
            l += __shfl_xor(l, 1);
            l += __shfl_xor(l, 2);
            l += __shfl_xor(l, 4);
            l += __shfl_xor(l, 8);
            float ldv = __shfl(ld, 2 * (m * 16 + lg * 4 + reg));
            if (lr == 0) ssum += ldv + LN2f * __builtin_amdgcn_logf(l);
        }
    ssum += __shfl_xor(ssum, 16);
    ssum += __shfl_xor(ssum, 32);

    __shared__ float red[4];
    if (lane == 0) red[w] = ssum;
    __syncthreads();
    if (tid == 0) partials[blockIdx.x] = red[0] + red[1] + red[2] + red[3];
}

// Kernel 3: deterministic reduction of per-block partials -> mean.
__global__ void dce_finish(const float* __restrict__ partials,
                           float* __restrict__ out, int nblocks, float invN) {
    int tid = threadIdx.x;  // 256
    float s = 0.f;
    for (int i = tid; i < nblocks; i += 256) s += partials[i];
#pragma unroll
    for (int d = 1; d < 64; d <<= 1) s += __shfl_xor(s, d);
    __shared__ float red[4];
    if ((tid & 63) == 0) red[tid >> 6] = s;
    __syncthreads();
    if (tid == 0) out[0] = (red[0] + red[1] + red[2] + red[3]) * invN;
}

extern "C" void kernel_launch(void* const* d_in, const int* in_sizes, int n_in,
                              void* d_out, int out_size, void* d_ws, size_t ws_size,
                              hipStream_t stream) {
    const float* feats = (const float*)d_in[0];
    const float* protos = (const float*)d_in[1];
    const int* labels = (const int*)d_in[2];
    const int N = in_sizes[2];          // 262144
    const int C = in_sizes[1] / 128;    // 1024
    float* out = (float*)d_out;

    // Workspace: [bpf: C*128*2B][ysq2: C*4B][partials: N/128*4B]
    unsigned short* bpf = (unsigned short*)d_ws;
    float* ysq2 = (float*)((char*)d_ws + (size_t)C * 128 * 2);
    float* partials = ysq2 + C;
    const int nblocks = N / 128;

    dce_prep<<<C, 64, 0, stream>>>(protos, bpf, ysq2);
    dce_main<<<nblocks, 256, 0, stream>>>(feats, protos, bpf, ysq2, labels, partials, C);
    dce_finish<<<1, 256, 0, stream>>>(partials, out, nblocks, 1.0f / (float)N);
}

// Round 7
// 133.909 us; speedup vs baseline: 1.2623x; 1.2623x over previous
//
#include <hip/hip_runtime.h>
#include <hip/hip_bf16.h>

typedef __bf16 bf16x8 __attribute__((ext_vector_type(8)));
typedef __bf16 bf16x2 __attribute__((ext_vector_type(2)));
typedef float f32x4 __attribute__((ext_vector_type(4)));

#define K2f 2.0813689810056077f   // log2(e)^2
#define LN2f 0.6931471805599453f

// Kernel 1: prototypes f32 -> bf16 in MFMA B-fragment order + ysq2 = ||y||^2*log2e^2.
// Element e of class c, dim d (d = kk*32 + lg*8 + e) -> bf16 offset
// ((c>>4)*4 + kk)*64*8 + (lg*16 + (c&15))*8 + e.  Tile ct occupies 4096 B.
__global__ void dce_prep(const float* __restrict__ protos,
                         unsigned short* __restrict__ bpf,
                         float* __restrict__ ysq2) {
    int c = blockIdx.x;
    int lane = threadIdx.x;  // dims 2*lane, 2*lane+1
    float2 f = ((const float2*)(protos))[c * 64 + lane];
    int d0 = lane * 2;
    int kk = d0 >> 5, sub = d0 & 31, lg = sub >> 3, e = sub & 7;
    size_t o = (((size_t)((c >> 4) * 4 + kk) * 64) + lg * 16 + (c & 15)) * 8 + e;
    bf16x2 h;
    h.x = (__bf16)f.x;
    h.y = (__bf16)f.y;
    *(bf16x2*)(bpf + o) = h;
    float xs = f.x * f.x + f.y * f.y;
#pragma unroll
    for (int d = 1; d < 64; d <<= 1) xs += __shfl_xor(xs, d);
    if (lane == 0) ysq2[c] = xs * K2f;
}

// Kernel 2: fused distance-softmax-NLL. No barriers, no LDS staging: each wave
// streams frag-ordered B from L1/L2 with a depth-1 ping-pong register
// prefetch (all loads unconditional; last 2 tiles peeled). 2048 blocks x 256
// threads; wave owns 32 rows (2 M-frags). logits <= 0 -> softmax max pinned
// at 0:  nll = dist_label + ln2 * log2( sum_c 2^(-log2e * dist_c) ).
__global__ __launch_bounds__(256, 4) void dce_main(
    const float* __restrict__ feats,
    const float* __restrict__ protos,
    const unsigned short* __restrict__ bpf,
    const float* __restrict__ ysq2,
    const int* __restrict__ labels,
    float* __restrict__ partials, int C) {
    const int tid = threadIdx.x;
    const int lane = tid & 63;
    const int w = tid >> 6;
    const int row0 = blockIdx.x * 128;
    const int rbase = row0 + w * 32;
    const int lr = lane & 15;
    const int lg = lane >> 4;

    // ---- Phase 1: exact f32 label distance, 2 threads per row ----
    const int r1 = row0 + (tid >> 1);
    const int half = tid & 1;
    const int lab = labels[r1];
    const float4* fx = (const float4*)feats + (size_t)r1 * 32 + half * 16;
    const float4* px = (const float4*)protos + (size_t)lab * 32 + half * 16;
    float xx = 0.f, yy = 0.f, xy = 0.f;
#pragma unroll
    for (int i = 0; i < 16; ++i) {
        float4 f = fx[i], p = px[i];
        xx = fmaf(f.x, f.x, fmaf(f.y, f.y, fmaf(f.z, f.z, fmaf(f.w, f.w, xx))));
        yy = fmaf(p.x, p.x, fmaf(p.y, p.y, fmaf(p.z, p.z, fmaf(p.w, p.w, yy))));
        xy = fmaf(f.x, p.x, fmaf(f.y, p.y, fmaf(f.z, p.z, fmaf(f.w, p.w, xy))));
    }
    xx += __shfl_xor(xx, 1);
    yy += __shfl_xor(yy, 1);
    xy += __shfl_xor(xy, 1);
    const float ld = __builtin_amdgcn_sqrtf(fmaxf(fmaf(-2.f, xy, xx + yy), 0.f));

    // ---- A fragments: 2 M-frags x 4 k-slices ----
    bf16x8 a[2][4];
    const float4* f4 = (const float4*)feats;
#pragma unroll
    for (int m = 0; m < 2; ++m) {
        size_t r = (size_t)(rbase + m * 16 + lr);
#pragma unroll
        for (int kk = 0; kk < 4; ++kk) {
            size_t idx = r * 32 + kk * 8 + lg * 2;
            float4 lo = f4[idx];
            float4 hi = f4[idx + 1];
            bf16x8 v;
            v[0] = (__bf16)lo.x; v[1] = (__bf16)lo.y; v[2] = (__bf16)lo.z; v[3] = (__bf16)lo.w;
            v[4] = (__bf16)hi.x; v[5] = (__bf16)hi.y; v[6] = (__bf16)hi.z; v[7] = (__bf16)hi.w;
            a[m][kk] = v;
        }
    }

    // ||x||^2 (scaled) in C/D layout: element (m,reg) covers row m*16+lg*4+reg,
    // whose exact xx lives at lane 2*(that row-in-wave).
    float xsqs[2][4];
#pragma unroll
    for (int m = 0; m < 2; ++m)
#pragma unroll
        for (int reg = 0; reg < 4; ++reg)
            xsqs[m][reg] = K2f * __shfl(xx, 2 * (m * 16 + lg * 4 + reg));

    float lacc[2][4];
#pragma unroll
    for (int m = 0; m < 2; ++m)
#pragma unroll
        for (int reg = 0; reg < 4; ++reg) lacc[m][reg] = 0.f;

    const bf16x8* bv = (const bf16x8*)bpf;

#define LOADB(dst, yq, t)                                         \
    {                                                             \
        _Pragma("unroll") for (int kk = 0; kk < 4; ++kk)          \
            dst[kk] = bv[(size_t)((t) * 4 + kk) * 64 + lane];     \
        yq = ysq2[(t) * 16 + lr];                                 \
    }

#define COMPUTE(b, yq)                                                          \
    {                                                                           \
        _Pragma("unroll") for (int m = 0; m < 2; ++m) {                         \
            f32x4 acc = {0.f, 0.f, 0.f, 0.f};                                   \
            acc = __builtin_amdgcn_mfma_f32_16x16x32_bf16(a[m][0], b[0], acc, 0, 0, 0); \
            acc = __builtin_amdgcn_mfma_f32_16x16x32_bf16(a[m][1], b[1], acc, 0, 0, 0); \
            acc = __builtin_amdgcn_mfma_f32_16x16x32_bf16(a[m][2], b[2], acc, 0, 0, 0); \
            acc = __builtin_amdgcn_mfma_f32_16x16x32_bf16(a[m][3], b[3], acc, 0, 0, 0); \
            _Pragma("unroll") for (int reg = 0; reg < 4; ++reg) {               \
                float d = fmaf(-2.f * K2f, acc[reg], xsqs[m][reg] + yq);        \
                d = fmaxf(d, 0.f);                                              \
                float s = __builtin_amdgcn_sqrtf(d);                            \
                lacc[m][reg] += __builtin_amdgcn_exp2f(-s);                     \
            }                                                                   \
        }                                                                       \
    }

    // ---- Main loop: depth-1 ping-pong register prefetch over 64 B tiles ----
    bf16x8 bA[4], bB[4];
    float yqA, yqB;
    LOADB(bA, yqA, 0);
    const int nt = C >> 4;  // 64 (even)
    for (int t = 0; t < nt - 2; t += 2) {
        LOADB(bB, yqB, t + 1);
        COMPUTE(bA, yqA);        // tile t   (overlaps bB loads)
        LOADB(bA, yqA, t + 2);
        COMPUTE(bB, yqB);        // tile t+1 (overlaps bA loads)
    }
    LOADB(bB, yqB, nt - 1);
    COMPUTE(bA, yqA);            // tile nt-2
    COMPUTE(bB, yqB);            // tile nt-1

#undef LOADB
#undef COMPUTE

    // ---- Reduce over 16 column-lanes per row, add exact label distance ----
    float ssum = 0.f;
#pragma unroll
    for (int m = 0; m < 2; ++m)
#pragma unroll
        for (int reg = 0; reg < 4; ++reg) {
            float l = lacc[m][reg];
            l += __shfl_xor(l, 1);
            l += __shfl_xor(l, 2);
            l += __shfl_xor(l, 4);
            l += __shfl_xor(l, 8);
            float ldv = __shfl(ld, 2 * (m * 16 + lg * 4 + reg));
            if (lr == 0) ssum += ldv + LN2f * __builtin_amdgcn_logf(l);
        }
    ssum += __shfl_xor(ssum, 16);
    ssum += __shfl_xor(ssum, 32);

    __shared__ float red[4];
    if (lane == 0) red[w] = ssum;
    __syncthreads();
    if (tid == 0) partials[blockIdx.x] = red[0] + red[1] + red[2] + red[3];
}

// Kernel 3: deterministic reduction of per-block partials -> mean.
__global__ void dce_finish(const float* __restrict__ partials,
                           float* __restrict__ out, int nblocks, float invN) {
    int tid = threadIdx.x;  // 256
    float s = 0.f;
    for (int i = tid; i < nblocks; i += 256) s += partials[i];
#pragma unroll
    for (int d = 1; d < 64; d <<= 1) s += __shfl_xor(s, d);
    __shared__ float red[4];
    if ((tid & 63) == 0) red[tid >> 6] = s;
    __syncthreads();
    if (tid == 0) out[0] = (red[0] + red[1] + red[2] + red[3]) * invN;
}

extern "C" void kernel_launch(void* const* d_in, const int* in_sizes, int n_in,
                              void* d_out, int out_size, void* d_ws, size_t ws_size,
                              hipStream_t stream) {
    const float* feats = (const float*)d_in[0];
    const float* protos = (const float*)d_in[1];
    const int* labels = (const int*)d_in[2];
    const int N = in_sizes[2];          // 262144
    const int C = in_sizes[1] / 128;    // 1024
    float* out = (float*)d_out;

    // Workspace: [bpf: C*128*2B][ysq2: C*4B][partials: N/128*4B]
    unsigned short* bpf = (unsigned short*)d_ws;
    float* ysq2 = (float*)((char*)d_ws + (size_t)C * 128 * 2);
    float* partials = ysq2 + C;
    const int nblocks = N / 128;

    dce_prep<<<C, 64, 0, stream>>>(protos, bpf, ysq2);
    dce_main<<<nblocks, 256, 0, stream>>>(feats, protos, bpf, ysq2, labels, partials, C);
    dce_finish<<<1, 256, 0, stream>>>(partials, out, nblocks, 1.0f / (float)N);
}